// Round 14
// baseline (210.428 us; speedup 1.0000x reference)
//
#include <hip/hip_runtime.h>
#include <hip/hip_bf16.h>
#include <math.h>

// Problem constants
#define BB 2
#define CC 64
#define HH 256
#define WW 256
#define OO 64
#define K2 9
#define HW 65536
#define CHW (CC*HW)

typedef _Float16 h8 __attribute__((ext_vector_type(8)));
typedef __fp16 fp16x2 __attribute__((ext_vector_type(2)));
typedef __attribute__((ext_vector_type(4))) unsigned int ux4;
typedef __attribute__((ext_vector_type(4))) float f32x4;

// Bijective XCD swizzle (nwg divisible by 8)
__device__ __forceinline__ int xcd_swz(int bid, int nwg) {
    const int per = nwg >> 3;
    return (bid & 7) * per + (bid >> 3);
}
__device__ __forceinline__ unsigned short f2h(float f) {
    _Float16 h = (_Float16)f;
    return __builtin_bit_cast(unsigned short, h);
}
__device__ __forceinline__ unsigned int pkrtz(float lo, float hi) {
    fp16x2 p = __builtin_amdgcn_cvt_pkrtz(lo, hi);
    return __builtin_bit_cast(unsigned int, p);
}
__device__ __forceinline__ h8 splat8(float f) {
    _Float16 h = (_Float16)f;
    h8 r = {h, h, h, h, h, h, h, h};
    return r;
}

// wA: [32 ch][576 s'] fp16, s' = tap*64 + c (tap-major K order). rows 27..31 = 0.
// wk: [9 k][64 o][64 c] fp16.
__global__ __launch_bounds__(256) void k_prep(
    const float* __restrict__ offw, const float* __restrict__ ampw,
    const float* __restrict__ w3d,
    unsigned short* __restrict__ wA, unsigned short* __restrict__ wk)
{
    int i = blockIdx.x * 256 + threadIdx.x;   // grid 216 -> 55296 exact
    if (i < 18432) {
        int ch = i / 576, sp = i % 576;
        int tap = sp >> 6, c = sp & 63;
        float v = 0.f;
        if (ch < 18)      v = offw[ch*576 + c*9 + tap];
        else if (ch < 27) v = ampw[(ch-18)*576 + c*9 + tap];
        wA[i] = f2h(v);
    } else if (i < 55296) {
        int j = i - 18432;
        int k = j >> 12, rem = j & 4095;
        int o = rem >> 6, c = rem & 63;
        wk[j] = f2h(w3d[o*576 + c*9 + k]);
    }
}

// Fused kernel. Block = 512 thr = 8 waves, owns (b, row-pair h0/h0+1, 64-col
// quarter), all 64 o. LDS = tile only (52.2 KB) -> 3 blocks/CU = 6 waves/SIMD.
// Conv outputs distributed wave-locally via __shfl (no ot16 LDS buffer).
__global__ __launch_bounds__(512, 6) void k_fused(
    const float* __restrict__ x, const unsigned short* __restrict__ wA,
    const unsigned short* __restrict__ wk,
    const float* __restrict__ offb, const float* __restrict__ ampb,
    float* __restrict__ out)
{
    // LDS map:
    //  tb [0,52224) : tile fp16, 408 planes (pp = rr*68+cc) x 128B (64 c),
    //                 16B-slot XOR-swizzled by (pp&7)
    //  epilogue: ct f32 [64][130] overlays tb.
    __shared__ __attribute__((aligned(16))) unsigned char lds[52224];
    unsigned char* tb = lds;

    const int tid = threadIdx.x;
    const int idx = xcd_swz(blockIdx.x, BB*(HH/2)*4);   // 1024 blocks
    const int wq = idx & 3, hp = (idx >> 2) & 127, b = idx >> 9;
    const int h0 = hp << 1, w0 = wq << 6;
    const int lane = tid & 63, wv = tid >> 6;
    const int lrow = lane & 15, lg = lane >> 4;

    const float* xb = x + (size_t)b * CHW;
    const int r0a = h0 - 2, c0a = w0 - 2;

    // ---- Phase 1: stage tile (abs rows h0-2..h0+3, cols w0-2..w0+65, 0 outside).
    // One plane per thread; channels in 4 chunks of 16 (register-lean).
    if (tid < 408) {
        const int rr = tid / 68;
        const int cc = tid - rr*68;
        const int ra = r0a + rr, ca = c0a + cc;
        const bool inb = ((unsigned)ra < 256u) && ((unsigned)ca < 256u);
        const float* ps = xb + ra*256 + ca;
        const int swz = (tid & 7) << 4;
#pragma unroll
        for (int ch = 0; ch < 64; ch += 16) {
            float v[16];
#pragma unroll
            for (int j = 0; j < 16; ++j)
                v[j] = inb ? ps[(size_t)(ch + j) * HW] : 0.f;
            ux4 q0, q1;
            q0[0] = pkrtz(v[0],  v[1]);
            q0[1] = pkrtz(v[2],  v[3]);
            q0[2] = pkrtz(v[4],  v[5]);
            q0[3] = pkrtz(v[6],  v[7]);
            q1[0] = pkrtz(v[8],  v[9]);
            q1[1] = pkrtz(v[10], v[11]);
            q1[2] = pkrtz(v[12], v[13]);
            q1[3] = pkrtz(v[14], v[15]);
            *(ux4*)(tb + tid*128 + ((ch*2     ) ^ swz)) = q0;
            *(ux4*)(tb + tid*128 + ((ch*2 + 16) ^ swz)) = q1;
        }
    }
    __syncthreads();

    // ---- Phase 2: offset/amp conv via MFMA (fp16). D[m=ch(32)][n=px(16/wave)],
    // K=576. Outputs stay in wave registers; distributed via shuffles below.
    float oyv[K2], oxv[K2], aav[K2];
    {
        f32x4 oacc0 = {0.f,0.f,0.f,0.f}, oacc1 = {0.f,0.f,0.f,0.f};
        const int pxl = wv*16 + lrow;           // 0..127
        const int prow2 = pxl >> 6, pcol2 = pxl & 63;
#pragma unroll
        for (int ks = 0; ks < 18; ++ks) {
            const int sbase = ks*32 + lg*8;
            const int tap = sbase >> 6;
            const int cb  = sbase & 63;
            const int ky = tap / 3, kx = tap - ky*3;
            const int pp = (prow2 + ky + 1)*68 + pcol2 + kx + 1;
            const h8 bf = *(const h8*)(tb + pp*128 + ((2*cb) ^ ((pp & 7) << 4)));
            const h8 a0 = *(const h8*)(wA + (      lrow)*576 + sbase);
            const h8 a1 = *(const h8*)(wA + (16 + lrow)*576 + sbase);
            oacc0 = __builtin_amdgcn_mfma_f32_16x16x32_f16(a0, bf, oacc0, 0, 0, 0);
            oacc1 = __builtin_amdgcn_mfma_f32_16x16x32_f16(a1, bf, oacc1, 0, 0, 0);
        }

        // Wave-local distribution: value for ch (<16: oacc0 of lane lg'=ch>>2,
        // reg ch&3; >=16: oacc1 of lane lg'=(ch-16)>>2, reg (ch-16)&3), px fixed
        // by lrow. All quad-mates need the same px params -> broadcast shuffles.
#pragma unroll
        for (int k = 0; k < K2; ++k) {
            const int cy = 2*k, cx = 2*k + 1, ca = 18 + k;
            const float vy = (cy < 16)
                ? __shfl(oacc0[cy & 3], lrow | ((cy >> 2) << 4), 64)
                : __shfl(oacc1[(cy - 16) & 3], lrow | (((cy - 16) >> 2) << 4), 64);
            const float vx = (cx < 16)
                ? __shfl(oacc0[cx & 3], lrow | ((cx >> 2) << 4), 64)
                : __shfl(oacc1[(cx - 16) & 3], lrow | (((cx - 16) >> 2) << 4), 64);
            const float va = __shfl(oacc1[(ca - 16) & 3], lrow | (((ca - 16) >> 2) << 4), 64);
            oyv[k] = vy + offb[cy];
            oxv[k] = vx + offb[cx];
            aav[k] = 1.f / (1.f + __expf(-(va + ampb[k])));
        }
    }

    // ---- Phase 3: fully-unrolled tap loop; head is register-only.
    const int px = wv*16 + lrow;          // this thread's A-row pixel (0..127)
    const int prow = px >> 6, pcol = px & 63;
    const int cA0 = lg*8;                 // fallback c-chunk bases
    const int cA1 = 32 + lg*8;
    const int cb0 = lg*16;                // byte offsets within a 128B plane
    const int cb1 = 64 + lg*16;

    f32x4 acc[4];
#pragma unroll
    for (int n = 0; n < 4; ++n) acc[n] = (f32x4){0.f, 0.f, 0.f, 0.f};

#pragma unroll
    for (int k = 0; k < K2; ++k) {
        // B-fragments for tap k, directly from global (L2-resident 8KB slice)
        h8 bf0[4], bf1[4];
        {
            const unsigned short* wb = wk + (size_t)k*4096 + lg*8;
#pragma unroll
            for (int n = 0; n < 4; ++n) {
                bf0[n] = *(const h8*)(wb + (n*16 + lrow)*64);
                bf1[n] = *(const h8*)(wb + (n*16 + lrow)*64 + 32);
            }
        }

        // sampling params for (px, tap k) — inputs already in registers
        const int ky = k / 3, kx = k - ky*3;
        const float aa = aav[k];
        float yy = (float)(h0 + prow + ky) + oyv[k];
        float xx = (float)(w0 + pcol + kx) + oxv[k];
        yy = fminf(fmaxf(yy, 0.f), 257.f);
        xx = fminf(fmaxf(xx, 0.f), 257.f);

        const float y0f = floorf(yy), x0f = floorf(xx);
        const float y1f = fminf(y0f + 1.f, 257.f);
        const float x1f = fminf(x0f + 1.f, 257.f);
        const float ay = yy - y0f, by = y1f - yy;
        const float ax = xx - x0f, bx = x1f - xx;
        const int r0 = (int)y0f - 1, r1 = (int)y1f - 1;
        const int c0 = (int)x0f - 1, c1 = (int)x1f - 1;
        const int rr0 = r0 - r0a, rr1 = r1 - r0a;
        const int cc0 = c0 - c0a, cc1 = c1 - c0a;
        const float w00 = by*bx*aa, w01 = by*ax*aa, w10 = ay*bx*aa, w11 = ay*ax*aa;

        h8 A0, A1;
        const bool ok = ((unsigned)rr0 <= 5u) && ((unsigned)rr1 <= 5u) &&
                        ((unsigned)cc0 <= 67u) && ((unsigned)cc1 <= 67u);
        if (ok) {
            const int pp00 = rr0*68 + cc0, pp01 = rr0*68 + cc1;
            const int pp10 = rr1*68 + cc0, pp11 = rr1*68 + cc1;
            const int s00 = (pp00 & 7) << 4, s01 = (pp01 & 7) << 4;
            const int s10 = (pp10 & 7) << 4, s11 = (pp11 & 7) << 4;
            const h8 Wb00 = splat8(w00), Wb01 = splat8(w01);
            const h8 Wb10 = splat8(w10), Wb11 = splat8(w11);

            auto bilerp8 = [&](int off) -> h8 {
                const h8 d00 = *(const h8*)(tb + pp00*128 + (off ^ s00));
                const h8 d01 = *(const h8*)(tb + pp01*128 + (off ^ s01));
                const h8 d10 = *(const h8*)(tb + pp10*128 + (off ^ s10));
                const h8 d11 = *(const h8*)(tb + pp11*128 + (off ^ s11));
                h8 t = d00 * Wb00;
                t = __builtin_elementwise_fma(d01, Wb01, t);
                t = __builtin_elementwise_fma(d10, Wb10, t);
                t = __builtin_elementwise_fma(d11, Wb11, t);
                return t;
            };
            A0 = bilerp8(cb0);
            A1 = bilerp8(cb1);
        } else {
            const bool vy0 = (unsigned)r0 < 256u, vy1 = (unsigned)r1 < 256u;
            const bool vx0 = (unsigned)c0 < 256u, vx1 = (unsigned)c1 < 256u;
            float W00 = w00, W01 = w01, W10 = w10, W11 = w11;
            int o00, o01, o10, o11;
            if (vy0 && vx0) o00 = r0*WW + c0; else { o00 = 0; W00 = 0.f; }
            if (vy0 && vx1) o01 = r0*WW + c1; else { o01 = 0; W01 = 0.f; }
            if (vy1 && vx0) o10 = r1*WW + c0; else { o10 = 0; W10 = 0.f; }
            if (vy1 && vx1) o11 = r1*WW + c1; else { o11 = 0; W11 = 0.f; }
            const float* pc0 = xb + (size_t)cA0 * HW;
            const float* pc1 = xb + (size_t)cA1 * HW;
#pragma unroll
            for (int jj = 0; jj < 8; ++jj) {
                float va = W00*pc0[o00] + W01*pc0[o01] + W10*pc0[o10] + W11*pc0[o11];
                pc0 += HW;
                A0[jj] = (_Float16)va;
                float vb = W00*pc1[o00] + W01*pc1[o01] + W10*pc1[o10] + W11*pc1[o11];
                pc1 += HW;
                A1[jj] = (_Float16)vb;
            }
        }

        // MFMA tap k: A-frags straight from registers
#pragma unroll
        for (int n = 0; n < 4; ++n)
            acc[n] = __builtin_amdgcn_mfma_f32_16x16x32_f16(A0, bf0[n], acc[n], 0, 0, 0);
#pragma unroll
        for (int n = 0; n < 4; ++n)
            acc[n] = __builtin_amdgcn_mfma_f32_16x16x32_f16(A1, bf1[n], acc[n], 0, 0, 0);
    }

    // ---- Epilogue: transpose via LDS (overlays tile) -> coalesced ReLU stores
    __syncthreads();
    float* ct = (float*)lds;    // [64 o][130]
#pragma unroll
    for (int n = 0; n < 4; ++n)
#pragma unroll
        for (int r = 0; r < 4; ++r)
            ct[(n*16 + lrow)*130 + wv*16 + lg*4 + r] = acc[n][r];
    __syncthreads();

    const size_t ob = (size_t)b*OO*HW + (size_t)h0*WW + w0;
#pragma unroll
    for (int it = 0; it < 16; ++it) {
        const int o = it*4 + (wv & 3);
        const int row = wv >> 2;
        out[ob + (size_t)o*HW + row*WW + lane] =
            fmaxf(ct[o*130 + row*64 + lane], 0.f);
    }
}

extern "C" void kernel_launch(void* const* d_in, const int* in_sizes, int n_in,
                              void* d_out, int out_size, void* d_ws, size_t ws_size,
                              hipStream_t stream) {
    const float* x    = (const float*)d_in[0];
    const float* offw = (const float*)d_in[1];
    const float* offb = (const float*)d_in[2];
    const float* ampw = (const float*)d_in[3];
    const float* ampb = (const float*)d_in[4];
    const float* w3d  = (const float*)d_in[5];
    float* out = (float*)d_out;

    unsigned short* wA = (unsigned short*)d_ws;          // 18432 fp16
    unsigned short* wk = wA + 18432;                     // 36864 fp16

    k_prep<<<216, 256, 0, stream>>>(offw, ampw, w3d, wA, wk);
    k_fused<<<BB*(HH/2)*4, 512, 0, stream>>>(x, wA, wk, offb, ampb, out);
}

// Round 15
// 204.992 us; speedup vs baseline: 1.0265x; 1.0265x over previous
//
#include <hip/hip_runtime.h>
#include <hip/hip_bf16.h>
#include <math.h>

// Problem constants
#define BB 2
#define CC 64
#define HH 256
#define WW 256
#define OO 64
#define K2 9
#define HW 65536
#define CHW (CC*HW)

// x_t: fp16, padded pixel-major [B][258][258][64]
#define XTW 258
#define XT_ROW (XTW*64)          // 16512 els per padded row
#define XT_BATCH (XTW*XTW*64)    // 4,260,096 els per batch

// ws layout (bytes)
#define WA_B   0u                // 18432 fp16 = 36864 B
#define WK_B   36864u            // 36864 fp16 = 73728 B
#define XT_B   110592u           // 17,040,384 B (both batches)
#define OU_B   17151076u         // fixed below (aligned)
// recompute: XT_B + 17040384 = 17150976
#undef OU_B
#define OU_B   17150976u         // 2*9*HW uint = 4,718,592 B
#define AMP_B  21869568u         // 2*9*HW ushort = 2,359,296 B
// total = 24,228,864 B

typedef _Float16 h8 __attribute__((ext_vector_type(8)));
typedef __fp16 fp16x2 __attribute__((ext_vector_type(2)));
typedef __attribute__((ext_vector_type(4))) unsigned int ux4;
typedef __attribute__((ext_vector_type(4))) float f32x4;

__device__ __forceinline__ int xcd_swz(int bid, int nwg) {
    const int per = nwg >> 3;
    return (bid & 7) * per + (bid >> 3);
}
__device__ __forceinline__ unsigned short f2h(float f) {
    _Float16 h = (_Float16)f;
    return __builtin_bit_cast(unsigned short, h);
}
__device__ __forceinline__ float h2f(unsigned short u) {
    return (float)__builtin_bit_cast(_Float16, u);
}
__device__ __forceinline__ unsigned int pkrtz(float lo, float hi) {
    fp16x2 p = __builtin_amdgcn_cvt_pkrtz(lo, hi);
    return __builtin_bit_cast(unsigned int, p);
}
__device__ __forceinline__ h8 splat8(float f) {
    _Float16 h = (_Float16)f;
    h8 r = {h, h, h, h, h, h, h, h};
    return r;
}

// K1: blocks 0..511 transpose x -> x_t (padded, interior); 512..727 weight prep.
// wA: [32 ch][576 s'] fp16, s' = tap*64 + c. wk: [9 k][64 o][64 c] fp16.
__global__ __launch_bounds__(256) void k_pre(
    const float* __restrict__ x, const float* __restrict__ offw,
    const float* __restrict__ ampw, const float* __restrict__ w3d,
    unsigned short* __restrict__ wA, unsigned short* __restrict__ wk,
    unsigned short* __restrict__ xt)
{
    const int tid = threadIdx.x;
    const int id = blockIdx.x;
    if (id < 512) {
        __shared__ __attribute__((aligned(16))) unsigned char tl[32768];
        const int b = id >> 8, h = id & 255;
        const float* xb = x + (size_t)b*CHW + h*256;
        const int wv = tid >> 6, lane = tid & 63;
        // read: wave wv covers c in [wv*16, wv*16+16), all 256 px; pack pairs.
        for (int ip = 0; ip < 8; ++ip) {
            const int c0 = wv*16 + ip*2;
            const float* p0 = xb + (size_t)c0*HW;
#pragma unroll
            for (int j = 0; j < 4; ++j) {
                const int px = j*64 + lane;
                const float v0 = p0[px];
                const float v1 = p0[HW + px];
                *(unsigned int*)(tl + px*128 + ((2*c0) ^ ((px & 7) << 4))) =
                    pkrtz(v0, v1);
            }
        }
        __syncthreads();
        // write: x_t row r=h+1, cols 1..256 (cooperative 2KB chunks)
        const int lrow = lane & 15, lg = lane >> 4;
        unsigned char* rowp = (unsigned char*)(xt + (size_t)b*XT_BATCH +
                                               (size_t)(h+1)*XT_ROW + 64);
#pragma unroll
        for (int g = 0; g < 4; ++g) {
            const int px = wv*64 + g*16 + lrow;
            const int swz = (px & 7) << 4;
            const ux4 a = *(const ux4*)(tl + px*128 + ((lg*16) ^ swz));
            const ux4 c = *(const ux4*)(tl + px*128 + ((64 + lg*16) ^ swz));
            *(ux4*)(rowp + (size_t)px*128 + lg*16) = a;
            *(ux4*)(rowp + (size_t)px*128 + 64 + lg*16) = c;
        }
    } else {
        int i = (id - 512)*256 + tid;      // 216 blocks -> 55296 exact
        if (i < 18432) {
            int ch = i / 576, sp = i % 576;
            int tap = sp >> 6, c = sp & 63;
            float v = 0.f;
            if (ch < 18)      v = offw[ch*576 + c*9 + tap];
            else if (ch < 27) v = ampw[(ch-18)*576 + c*9 + tap];
            wA[i] = f2h(v);
        } else if (i < 55296) {
            int j = i - 18432;
            int k = j >> 12, rem = j & 4095;
            int o = rem >> 6, c = rem & 63;
            wk[j] = f2h(w3d[o*576 + c*9 + k]);
        }
    }
}

// K2: offset/amp conv via MFMA, fragments read from x_t (global, L2/L3-hot).
// Block = 256 thr / 4 waves, 64 px. No LDS. Stores packed (oy,ox) + amp.
__global__ __launch_bounds__(256, 4) void k_off(
    const unsigned short* __restrict__ xt, const unsigned short* __restrict__ wA,
    const float* __restrict__ offb, const float* __restrict__ ampb,
    unsigned int* __restrict__ ou, unsigned short* __restrict__ amp)
{
    const int idx = xcd_swz(blockIdx.x, 2048);
    const int wq = idx & 3, h = (idx >> 2) & 255, b = idx >> 10;
    const int w0 = wq << 6;
    const int lane = threadIdx.x & 63, wv = threadIdx.x >> 6;
    const int lrow = lane & 15, lg = lane >> 4;
    const int pxa = w0 + wv*16 + lrow;      // output col 0..255
    const unsigned short* xtb = xt + (size_t)b*XT_BATCH;

    f32x4 o0 = {0.f,0.f,0.f,0.f}, o1 = {0.f,0.f,0.f,0.f};
#pragma unroll
    for (int ks = 0; ks < 18; ++ks) {
        const int sbase = ks*32 + lg*8;
        const int tap = sbase >> 6, cb = sbase & 63;
        const int ky = tap/3, kx = tap - 3*ky;
        const h8 bf = *(const h8*)(xtb + (size_t)(h + ky)*XT_ROW +
                                   (size_t)(pxa + kx)*64 + cb);
        const h8 a0 = *(const h8*)(wA + lrow*576 + sbase);
        const h8 a1 = *(const h8*)(wA + (16 + lrow)*576 + sbase);
        o0 = __builtin_amdgcn_mfma_f32_16x16x32_f16(a0, bf, o0, 0, 0, 0);
        o1 = __builtin_amdgcn_mfma_f32_16x16x32_f16(a1, bf, o1, 0, 0, 0);
    }
    // thread holds D[ch=lg*4+r][px] (o0: ch 0..15) and D[16+lg*4+r][px] (o1).
    const size_t pix = (size_t)h*256 + pxa;
    {
        const int k0 = 2*lg;        // taps 2lg, 2lg+1 from o0
        ou[(size_t)(b*9 + k0    )*HW + pix] =
            (unsigned int)f2h(o0[0] + offb[4*lg    ]) |
            ((unsigned int)f2h(o0[1] + offb[4*lg + 1]) << 16);
        ou[(size_t)(b*9 + k0 + 1)*HW + pix] =
            (unsigned int)f2h(o0[2] + offb[4*lg + 2]) |
            ((unsigned int)f2h(o0[3] + offb[4*lg + 3]) << 16);
        if (lg == 0)                // tap 8 from o1 (ch 16,17)
            ou[(size_t)(b*9 + 8)*HW + pix] =
                (unsigned int)f2h(o1[0] + offb[16]) |
                ((unsigned int)f2h(o1[1] + offb[17]) << 16);
    }
#pragma unroll
    for (int r = 0; r < 4; ++r) {   // amp: ch 18..26 -> k = ch-18
        const int ch = 16 + lg*4 + r;
        if (ch >= 18 && ch < 27) {
            const int k = ch - 18;
            const float s = 1.f / (1.f + __expf(-(o1[r] + ampb[k])));
            amp[(size_t)(b*9 + k)*HW + pix] = f2h(s);
        }
    }
}

// K3: deformable sampling (global gathers from x_t) + MFMA contraction + ReLU.
// Block = 256 thr / 4 waves, 64 px x all 64 o. LDS = epilogue only (16.9 KB).
__global__ __launch_bounds__(256, 4) void k_main(
    const unsigned short* __restrict__ xt, const unsigned short* __restrict__ wk,
    const unsigned int* __restrict__ ou, const unsigned short* __restrict__ amp,
    float* __restrict__ out)
{
    __shared__ __attribute__((aligned(16))) float ct[64*66];
    const int idx = xcd_swz(blockIdx.x, 2048);
    const int wq = idx & 3, h = (idx >> 2) & 255, b = idx >> 10;
    const int w0 = wq << 6;
    const int lane = threadIdx.x & 63, wv = threadIdx.x >> 6;
    const int lrow = lane & 15, lg = lane >> 4;
    const int pxl = wv*16 + lrow;           // 0..63
    const int pxa = w0 + pxl;
    const unsigned char* xtb = (const unsigned char*)(xt + (size_t)b*XT_BATCH);
    const size_t pix = (size_t)h*256 + pxa;

    // hoist all per-tap params into registers
    float oyv[K2], oxv[K2], aav[K2];
#pragma unroll
    for (int k = 0; k < K2; ++k) {
        const unsigned int u = ou[(size_t)(b*9 + k)*HW + pix];
        oyv[k] = h2f((unsigned short)(u & 0xffffu));
        oxv[k] = h2f((unsigned short)(u >> 16));
        aav[k] = h2f(amp[(size_t)(b*9 + k)*HW + pix]);
    }

    f32x4 acc[4];
#pragma unroll
    for (int n = 0; n < 4; ++n) acc[n] = (f32x4){0.f, 0.f, 0.f, 0.f};

    const int cb0 = lg*16;          // byte offsets within a 128B px-chunk
    const int cb1 = 64 + lg*16;

#pragma unroll
    for (int k = 0; k < K2; ++k) {
        // B-fragments for tap k (L2-resident)
        h8 bf0[4], bf1[4];
        {
            const unsigned short* wb = wk + (size_t)k*4096 + lg*8;
#pragma unroll
            for (int n = 0; n < 4; ++n) {
                bf0[n] = *(const h8*)(wb + (n*16 + lrow)*64);
                bf1[n] = *(const h8*)(wb + (n*16 + lrow)*64 + 32);
            }
        }

        const int ky = k/3, kx = k - 3*ky;
        float yy = (float)(h + ky) + oyv[k];
        float xx = (float)(pxa + kx) + oxv[k];
        yy = fminf(fmaxf(yy, 0.f), 257.f);
        xx = fminf(fmaxf(xx, 0.f), 257.f);
        const float y0f = floorf(yy), x0f = floorf(xx);
        const float y1f = fminf(y0f + 1.f, 257.f);
        const float x1f = fminf(x0f + 1.f, 257.f);
        const float ay = yy - y0f, by = y1f - yy;
        const float ax = xx - x0f, bx = x1f - xx;
        const int y0 = (int)y0f, y1 = (int)y1f;
        const int x0i = (int)x0f, x1i = (int)x1f;
        const float aa = aav[k];
        const h8 W00 = splat8(by*bx*aa), W01 = splat8(by*ax*aa);
        const h8 W10 = splat8(ay*bx*aa), W11 = splat8(ay*ax*aa);

        // all corners in [0,257] -> always in-bounds in padded x_t
        const size_t a00 = ((size_t)(y0*XTW + x0i)) * 128;
        const size_t a01 = ((size_t)(y0*XTW + x1i)) * 128;
        const size_t a10 = ((size_t)(y1*XTW + x0i)) * 128;
        const size_t a11 = ((size_t)(y1*XTW + x1i)) * 128;

        h8 A0, A1;
        {
            const h8 d00 = *(const h8*)(xtb + a00 + cb0);
            const h8 d01 = *(const h8*)(xtb + a01 + cb0);
            const h8 d10 = *(const h8*)(xtb + a10 + cb0);
            const h8 d11 = *(const h8*)(xtb + a11 + cb0);
            h8 t = d00 * W00;
            t = __builtin_elementwise_fma(d01, W01, t);
            t = __builtin_elementwise_fma(d10, W10, t);
            t = __builtin_elementwise_fma(d11, W11, t);
            A0 = t;
            const h8 e00 = *(const h8*)(xtb + a00 + cb1);
            const h8 e01 = *(const h8*)(xtb + a01 + cb1);
            const h8 e10 = *(const h8*)(xtb + a10 + cb1);
            const h8 e11 = *(const h8*)(xtb + a11 + cb1);
            h8 u = e00 * W00;
            u = __builtin_elementwise_fma(e01, W01, u);
            u = __builtin_elementwise_fma(e10, W10, u);
            u = __builtin_elementwise_fma(e11, W11, u);
            A1 = u;
        }

#pragma unroll
        for (int n = 0; n < 4; ++n)
            acc[n] = __builtin_amdgcn_mfma_f32_16x16x32_f16(A0, bf0[n], acc[n], 0, 0, 0);
#pragma unroll
        for (int n = 0; n < 4; ++n)
            acc[n] = __builtin_amdgcn_mfma_f32_16x16x32_f16(A1, bf1[n], acc[n], 0, 0, 0);
    }

    // epilogue: LDS transpose -> coalesced ReLU stores
#pragma unroll
    for (int n = 0; n < 4; ++n)
#pragma unroll
        for (int r = 0; r < 4; ++r)
            ct[(n*16 + lrow)*66 + wv*16 + lg*4 + r] = acc[n][r];
    __syncthreads();

    const size_t ob = (size_t)b*OO*HW + (size_t)h*WW + w0;
#pragma unroll
    for (int it = 0; it < 16; ++it) {
        const int o = it*4 + wv;
        out[ob + (size_t)o*HW + lane] = fmaxf(ct[o*66 + lane], 0.f);
    }
}

extern "C" void kernel_launch(void* const* d_in, const int* in_sizes, int n_in,
                              void* d_out, int out_size, void* d_ws, size_t ws_size,
                              hipStream_t stream) {
    const float* x    = (const float*)d_in[0];
    const float* offw = (const float*)d_in[1];
    const float* offb = (const float*)d_in[2];
    const float* ampw = (const float*)d_in[3];
    const float* ampb = (const float*)d_in[4];
    const float* w3d  = (const float*)d_in[5];
    float* out = (float*)d_out;

    unsigned char* ws = (unsigned char*)d_ws;
    unsigned short* wA  = (unsigned short*)(ws + WA_B);
    unsigned short* wk  = (unsigned short*)(ws + WK_B);
    unsigned short* xt  = (unsigned short*)(ws + XT_B);
    unsigned int*   ouP = (unsigned int*)(ws + OU_B);
    unsigned short* amP = (unsigned short*)(ws + AMP_B);

    hipMemsetAsync(xt, 0, (size_t)BB*XT_BATCH*2, stream);   // zero halo
    k_pre<<<728, 256, 0, stream>>>(x, offw, ampw, w3d, wA, wk, xt);
    k_off<<<2048, 256, 0, stream>>>(xt, wA, offb, ampb, ouP, amP);
    k_main<<<2048, 256, 0, stream>>>(xt, wk, ouP, amP, out);
}

// Round 16
// 200.121 us; speedup vs baseline: 1.0515x; 1.0243x over previous
//
#include <hip/hip_runtime.h>
#include <hip/hip_bf16.h>
#include <math.h>

// Problem constants
#define BB 2
#define CC 64
#define HH 256
#define WW 256
#define OO 64
#define K2 9
#define HW 65536
#define CHW (CC*HW)

// x_t: fp16, padded pixel-major [B][258][258][64]
#define XTW 258
#define XT_ROW (XTW*64)          // ushorts per padded row
#define XT_BATCH (XTW*XTW*64)

// ws layout (bytes)
#define WA_B   0u                // 18432 fp16
#define WK_B   36864u            // 36864 fp16
#define XT_B   110592u           // 17,040,384 B

typedef _Float16 h8 __attribute__((ext_vector_type(8)));
typedef __fp16 fp16x2 __attribute__((ext_vector_type(2)));
typedef __attribute__((ext_vector_type(4))) unsigned int ux4;
typedef __attribute__((ext_vector_type(4))) float f32x4;

__device__ __forceinline__ int xcd_swz(int bid, int nwg) {
    const int per = nwg >> 3;
    return (bid & 7) * per + (bid >> 3);
}
__device__ __forceinline__ unsigned short f2h(float f) {
    _Float16 h = (_Float16)f;
    return __builtin_bit_cast(unsigned short, h);
}
__device__ __forceinline__ unsigned int pkrtz(float lo, float hi) {
    fp16x2 p = __builtin_amdgcn_cvt_pkrtz(lo, hi);
    return __builtin_bit_cast(unsigned int, p);
}
__device__ __forceinline__ h8 splat8(float f) {
    _Float16 h = (_Float16)f;
    h8 r = {h, h, h, h, h, h, h, h};
    return r;
}

// K1: blocks 0..511 transpose x -> x_t (padded interior); 512..727 weight prep.
__global__ __launch_bounds__(256) void k_pre(
    const float* __restrict__ x, const float* __restrict__ offw,
    const float* __restrict__ ampw, const float* __restrict__ w3d,
    unsigned short* __restrict__ wA, unsigned short* __restrict__ wk,
    unsigned short* __restrict__ xt)
{
    const int tid = threadIdx.x;
    const int id = blockIdx.x;
    if (id < 512) {
        __shared__ __attribute__((aligned(16))) unsigned char tl[32768];
        const int b = id >> 8, h = id & 255;
        const float* xb = x + (size_t)b*CHW + h*256;
        const int wv = tid >> 6, lane = tid & 63;
        for (int ip = 0; ip < 8; ++ip) {
            const int c0 = wv*16 + ip*2;
            const float* p0 = xb + (size_t)c0*HW;
#pragma unroll
            for (int j = 0; j < 4; ++j) {
                const int px = j*64 + lane;
                const float v0 = p0[px];
                const float v1 = p0[HW + px];
                *(unsigned int*)(tl + px*128 + ((2*c0) ^ ((px & 7) << 4))) =
                    pkrtz(v0, v1);
            }
        }
        __syncthreads();
        const int lrow = lane & 15, lg = lane >> 4;
        unsigned char* rowp = (unsigned char*)(xt + (size_t)b*XT_BATCH +
                                               (size_t)(h+1)*XT_ROW + 64);
#pragma unroll
        for (int g = 0; g < 4; ++g) {
            const int px = wv*64 + g*16 + lrow;
            const int swz = (px & 7) << 4;
            const ux4 a = *(const ux4*)(tl + px*128 + ((lg*16) ^ swz));
            const ux4 c = *(const ux4*)(tl + px*128 + ((64 + lg*16) ^ swz));
            *(ux4*)(rowp + (size_t)px*128 + lg*16) = a;
            *(ux4*)(rowp + (size_t)px*128 + 64 + lg*16) = c;
        }
    } else {
        int i = (id - 512)*256 + tid;
        if (i < 18432) {
            int ch = i / 576, sp = i % 576;
            int tap = sp >> 6, c = sp & 63;
            float v = 0.f;
            if (ch < 18)      v = offw[ch*576 + c*9 + tap];
            else if (ch < 27) v = ampw[(ch-18)*576 + c*9 + tap];
            wA[i] = f2h(v);
        } else if (i < 55296) {
            int j = i - 18432;
            int k = j >> 12, rem = j & 4095;
            int o = rem >> 6, c = rem & 63;
            wk[j] = f2h(w3d[o*576 + c*9 + k]);
        }
    }
}

// K2: fused conv (MFMA from x_t) + shfl param distribution + pipelined
// deformable sampling (global gathers, 2-deep) + MFMA contraction + ReLU.
// Block = 256 thr / 4 waves, 64 px x all 64 o. LDS = epilogue only.
__global__ __launch_bounds__(256, 2) void k_fused2(
    const unsigned short* __restrict__ xt, const unsigned short* __restrict__ wA,
    const unsigned short* __restrict__ wk,
    const float* __restrict__ offb, const float* __restrict__ ampb,
    float* __restrict__ out)
{
    __shared__ __attribute__((aligned(16))) float ct[64*66];
    const int idx = xcd_swz(blockIdx.x, 2048);
    const int wq = idx & 3, h = (idx >> 2) & 255, b = idx >> 10;
    const int w0 = wq << 6;
    const int lane = threadIdx.x & 63, wv = threadIdx.x >> 6;
    const int lrow = lane & 15, lg = lane >> 4;
    const int pxa = w0 + wv*16 + lrow;      // this thread's pixel (col 0..255)
    const unsigned short* xtb16 = xt + (size_t)b*XT_BATCH;
    const unsigned char*  xtb   = (const unsigned char*)xtb16;

    // ---- Phase A: offset/amp conv via MFMA, frags straight from x_t.
    float oyv[K2], oxv[K2], aav[K2];
    {
        f32x4 o0 = {0.f,0.f,0.f,0.f}, o1 = {0.f,0.f,0.f,0.f};
#pragma unroll
        for (int ks = 0; ks < 18; ++ks) {
            const int sbase = ks*32 + lg*8;
            const int tap = sbase >> 6, cb = sbase & 63;
            const int ky = tap/3, kx = tap - 3*ky;
            const h8 bf = *(const h8*)(xtb16 + (size_t)(h + ky)*XT_ROW +
                                       (size_t)(pxa + kx)*64 + cb);
            const h8 a0 = *(const h8*)(wA + lrow*576 + sbase);
            const h8 a1 = *(const h8*)(wA + (16 + lrow)*576 + sbase);
            o0 = __builtin_amdgcn_mfma_f32_16x16x32_f16(a0, bf, o0, 0, 0, 0);
            o1 = __builtin_amdgcn_mfma_f32_16x16x32_f16(a1, bf, o1, 0, 0, 0);
        }
        // wave-local distribution (verified R14 mapping): D col=px(lane&15),
        // row=ch(lg*4+r). Thread needs ch-values for its px -> same lrow.
#pragma unroll
        for (int k = 0; k < K2; ++k) {
            const int cy = 2*k, cx = 2*k + 1, ca = 18 + k;
            const float vy = (cy < 16)
                ? __shfl(o0[cy & 3], lrow | ((cy >> 2) << 4), 64)
                : __shfl(o1[(cy - 16) & 3], lrow | (((cy - 16) >> 2) << 4), 64);
            const float vx = (cx < 16)
                ? __shfl(o0[cx & 3], lrow | ((cx >> 2) << 4), 64)
                : __shfl(o1[(cx - 16) & 3], lrow | (((cx - 16) >> 2) << 4), 64);
            const float va = __shfl(o1[(ca - 16) & 3], lrow | (((ca - 16) >> 2) << 4), 64);
            oyv[k] = vy + offb[cy];
            oxv[k] = vx + offb[cx];
            aav[k] = 1.f / (1.f + __expf(-(va + ampb[k])));
        }
    }

    // ---- Phase B: 2-deep pipelined tap loop.
    f32x4 acc[4];
#pragma unroll
    for (int n = 0; n < 4; ++n) acc[n] = (f32x4){0.f, 0.f, 0.f, 0.f};

    const int cb0 = lg*16;          // byte offsets within a 128B px-chunk
    const int cb1 = 64 + lg*16;

    h8 gA[8], gB[8];
    float wtA[4], wtB[4];

    // ISSUE: compute tap K's corner addrs+weights, start the 8 gathers.
#define ISSUE(K, G, WT)                                                        \
    {                                                                          \
        const int ky_ = (K)/3, kx_ = (K) - 3*ky_;                              \
        float yy_ = (float)(h + ky_) + oyv[(K)];                               \
        float xx_ = (float)(pxa + kx_) + oxv[(K)];                             \
        yy_ = fminf(fmaxf(yy_, 0.f), 257.f);                                   \
        xx_ = fminf(fmaxf(xx_, 0.f), 257.f);                                   \
        const float y0f_ = floorf(yy_), x0f_ = floorf(xx_);                    \
        const float y1f_ = fminf(y0f_ + 1.f, 257.f);                           \
        const float x1f_ = fminf(x0f_ + 1.f, 257.f);                           \
        const float ay_ = yy_ - y0f_, by_ = y1f_ - yy_;                        \
        const float ax_ = xx_ - x0f_, bx_ = x1f_ - xx_;                        \
        const float aa_ = aav[(K)];                                            \
        WT[0] = by_*bx_*aa_; WT[1] = by_*ax_*aa_;                              \
        WT[2] = ay_*bx_*aa_; WT[3] = ay_*ax_*aa_;                              \
        const int y0_ = (int)y0f_, y1_ = (int)y1f_;                            \
        const int x0_ = (int)x0f_, x1_ = (int)x1f_;                            \
        const size_t a00_ = ((size_t)(y0_*XTW + x0_)) * 128;                   \
        const size_t a01_ = ((size_t)(y0_*XTW + x1_)) * 128;                   \
        const size_t a10_ = ((size_t)(y1_*XTW + x0_)) * 128;                   \
        const size_t a11_ = ((size_t)(y1_*XTW + x1_)) * 128;                   \
        G[0] = *(const h8*)(xtb + a00_ + cb0);                                 \
        G[1] = *(const h8*)(xtb + a00_ + cb1);                                 \
        G[2] = *(const h8*)(xtb + a01_ + cb0);                                 \
        G[3] = *(const h8*)(xtb + a01_ + cb1);                                 \
        G[4] = *(const h8*)(xtb + a10_ + cb0);                                 \
        G[5] = *(const h8*)(xtb + a10_ + cb1);                                 \
        G[6] = *(const h8*)(xtb + a11_ + cb0);                                 \
        G[7] = *(const h8*)(xtb + a11_ + cb1);                                 \
    }

    // CONSUME: bilerp tap K from its buffer, load B-frags, 8 MFMA.
#define CONSUME(K, G, WT)                                                      \
    {                                                                          \
        h8 bf0_[4], bf1_[4];                                                   \
        const unsigned short* wb_ = wk + (size_t)(K)*4096 + lg*8;              \
        _Pragma("unroll")                                                      \
        for (int n = 0; n < 4; ++n) {                                          \
            bf0_[n] = *(const h8*)(wb_ + (n*16 + lrow)*64);                    \
            bf1_[n] = *(const h8*)(wb_ + (n*16 + lrow)*64 + 32);               \
        }                                                                      \
        const h8 W00_ = splat8(WT[0]), W01_ = splat8(WT[1]);                   \
        const h8 W10_ = splat8(WT[2]), W11_ = splat8(WT[3]);                   \
        h8 A0_ = G[0] * W00_;                                                  \
        A0_ = __builtin_elementwise_fma(G[2], W01_, A0_);                      \
        A0_ = __builtin_elementwise_fma(G[4], W10_, A0_);                      \
        A0_ = __builtin_elementwise_fma(G[6], W11_, A0_);                      \
        h8 A1_ = G[1] * W00_;                                                  \
        A1_ = __builtin_elementwise_fma(G[3], W01_, A1_);                      \
        A1_ = __builtin_elementwise_fma(G[5], W10_, A1_);                      \
        A1_ = __builtin_elementwise_fma(G[7], W11_, A1_);                      \
        _Pragma("unroll")                                                      \
        for (int n = 0; n < 4; ++n)                                            \
            acc[n] = __builtin_amdgcn_mfma_f32_16x16x32_f16(A0_, bf0_[n],      \
                                                            acc[n], 0, 0, 0);  \
        _Pragma("unroll")                                                      \
        for (int n = 0; n < 4; ++n)                                            \
            acc[n] = __builtin_amdgcn_mfma_f32_16x16x32_f16(A1_, bf1_[n],      \
                                                            acc[n], 0, 0, 0);  \
    }

    ISSUE(0, gA, wtA)
#pragma unroll
    for (int kp = 0; kp < 4; ++kp) {
        ISSUE(2*kp + 1, gB, wtB)
        CONSUME(2*kp, gA, wtA)
        ISSUE(2*kp + 2, gA, wtA)
        CONSUME(2*kp + 1, gB, wtB)
    }
    CONSUME(8, gA, wtA)
#undef ISSUE
#undef CONSUME

    // ---- Epilogue: LDS transpose -> coalesced ReLU stores
#pragma unroll
    for (int n = 0; n < 4; ++n)
#pragma unroll
        for (int r = 0; r < 4; ++r)
            ct[(n*16 + lrow)*66 + wv*16 + lg*4 + r] = acc[n][r];
    __syncthreads();

    const size_t ob = (size_t)b*OO*HW + (size_t)h*WW + w0;
#pragma unroll
    for (int it = 0; it < 16; ++it) {
        const int o = it*4 + wv;
        out[ob + (size_t)o*HW + lane] = fmaxf(ct[o*66 + lane], 0.f);
    }
}

extern "C" void kernel_launch(void* const* d_in, const int* in_sizes, int n_in,
                              void* d_out, int out_size, void* d_ws, size_t ws_size,
                              hipStream_t stream) {
    const float* x    = (const float*)d_in[0];
    const float* offw = (const float*)d_in[1];
    const float* offb = (const float*)d_in[2];
    const float* ampw = (const float*)d_in[3];
    const float* ampb = (const float*)d_in[4];
    const float* w3d  = (const float*)d_in[5];
    float* out = (float*)d_out;

    unsigned char* ws = (unsigned char*)d_ws;
    unsigned short* wA = (unsigned short*)(ws + WA_B);
    unsigned short* wk = (unsigned short*)(ws + WK_B);
    unsigned short* xt = (unsigned short*)(ws + XT_B);

    hipMemsetAsync(xt, 0, (size_t)BB*XT_BATCH*2, stream);   // zero halo
    k_pre<<<728, 256, 0, stream>>>(x, offw, ampw, w3d, wA, wk, xt);
    k_fused2<<<2048, 256, 0, stream>>>(xt, wA, wk, offb, ampb, out);
}